// Round 1
// 311.483 us; speedup vs baseline: 1.0767x; 1.0767x over previous
//
#include <hip/hip_runtime.h>
#include <type_traits>

#define NBATCH 32
#define NDIM 512

// ---- DPP cross-lane primitives (VALU-speed; no LDS, no barriers) ----

template <int CTRL, int RMASK>
__device__ __forceinline__ float dpp_add(float x) {
  int t = __builtin_amdgcn_update_dpp(0, __float_as_int(x), CTRL, RMASK, 0xf,
                                      false);
  return x + __int_as_float(t);
}

// wave64 inclusive prefix sum
__device__ __forceinline__ float prefix_inc(float x) {
  x = dpp_add<0x111, 0xf>(x);  // row_shr:1
  x = dpp_add<0x112, 0xf>(x);  // row_shr:2
  x = dpp_add<0x114, 0xf>(x);  // row_shr:4
  x = dpp_add<0x118, 0xf>(x);  // row_shr:8
  x = dpp_add<0x142, 0xa>(x);  // row_bcast:15 -> rows 1,3
  x = dpp_add<0x143, 0xc>(x);  // row_bcast:31 -> rows 2,3
  return x;
}

// shift one lane up (lane i gets lane i-1); lane 0 receives `fill`
__device__ __forceinline__ float wave_shr1(float x, float fill) {
  return __int_as_float(__builtin_amdgcn_update_dpp(
      __float_as_int(fill), __float_as_int(x), 0x138 /*wave_shr:1*/, 0xf, 0xf,
      false));
}

// one step of the wave64 inclusive affine-composition scan.
// Compose earlier-then-later: B = A*Be + B ; A = A*Ae. Identity = (1,0).
template <int CTRL, int RMASK>
__device__ __forceinline__ void aff_step(float& A, float& B) {
  float Ae = __int_as_float(__builtin_amdgcn_update_dpp(
      __float_as_int(1.0f), __float_as_int(A), CTRL, RMASK, 0xf, false));
  float Be = __int_as_float(__builtin_amdgcn_update_dpp(
      0, __float_as_int(B), CTRL, RMASK, 0xf, false));
  B = fmaf(A, Be, B);
  A = A * Ae;
}

// Workgroup barrier WITHOUT the vmcnt(0) drain __syncthreads() emits.
// Writer-side LDS ordering via lgkmcnt(0); trailing empty asm with a
// memory clobber stops the compiler hoisting post-barrier LDS reads.
// Global prefetch loads stay in flight across row barriers.
__device__ __forceinline__ void wg_barrier() {
  asm volatile("s_waitcnt lgkmcnt(0)" ::: "memory");
  __builtin_amdgcn_s_barrier();
  asm volatile("" ::: "memory");
}

// R14: 4-wave row split. One workgroup (4 waves, 256 threads) per batch
// element; wave w owns columns [128w, 128w+128), lane owns 2 columns.
// Per-row cross-wave coupling is 16 B of LDS: (1) per-wave t8-prefix
// totals for the linear guess, (2) per-wave affine totals (A,B).
// Predicate values are structurally identical to the single-wave R13
// kernel (guess at cell c == 1 - global t8-prefix before c; same
// continuous piecewise map), so the mispredict pattern and absmax are
// preserved up to fp reassociation.
__global__ __launch_bounds__(256, 1)
void sb_kernel(const float* __restrict__ x, const float* __restrict__ xm,
               float* __restrict__ out) {
  const int tid = (int)threadIdx.x;
  const int lane = tid & 63;
  const int w = __builtin_amdgcn_readfirstlane(tid >> 6);  // wave id 0..3
  const size_t base =
      (size_t)blockIdx.x * NDIM * NDIM + (size_t)(w * 128 + lane * 2);
  const float* xb = x + base;
  const float* mb = xm + base;
  float* ob = out + base;

  __shared__ alignas(16) float ex_sa[4];  // per-wave inclusive t8-sum totals
  __shared__ alignas(16) float ex_S[4];   // per-wave inclusive fu-sum totals
  __shared__ alignas(16) float ex_A[4];   // per-wave affine totals
  __shared__ alignas(16) float ex_B[4];

  // per-lane state for the 2 owned columns
  float w8_0, w8_1, t8_0, t8_1, pre1, sa;
  float fu0 = 0.0f, fu1 = 0.0f, suf0 = 0.0f, S = 0.0f;
  float wp0, wp1, sp0 = 0.0f, sp1 = 0.0f;
  float c1_0 = 0.0f, c1_1 = 0.0f, c2_0, c2_1, oc2_0, oc2_1;

  // 4 prefetch slots, one row each (8 B/lane, coalesced 512 B/wave)
  float2 x0, m0, x1, m1, x2, m2, x3, m3;
  x0 = *(const float2*)(xb);
  m0 = *(const float2*)(mb);
  x1 = *(const float2*)(xb + NDIM);
  m1 = *(const float2*)(mb + NDIM);
  x2 = *(const float2*)(xb + 2 * NDIM);
  m2 = *(const float2*)(mb + 2 * NDIM);
  x3 = *(const float2*)(xb + 3 * NDIM);
  m3 = *(const float2*)(mb + 3 * NDIM);

  auto build_pre = [&]() {
    pre1 = t8_0;
    sa = t8_0 + t8_1;
    wp0 = w8_0;         // w8 + pre(=0)
    wp1 = w8_1 + pre1;  // w8 + pre
  };
  auto build_suf = [&]() {
    suf0 = fu1;  // suf[1] = 0
    S = fu0 + fu1;
    sp0 = suf0;  // suf + pre(=0)
    sp1 = pre1;  // suf(=0) + pre
  };

  {  // row-0 prep: constants + scan inputs (w == 1, cs == 0)
    float s0 = __builtin_amdgcn_rcpf(1.0f + __expf(-x0.x));
    float s1 = __builtin_amdgcn_rcpf(1.0f + __expf(-x0.y));
    c2_0 = m0.x * s0;
    c2_1 = m0.y * s1;
    oc2_0 = 1.0f - c2_0;
    oc2_1 = 1.0f - c2_1;
    w8_0 = 1.0f;
    w8_1 = 1.0f;
    t8_0 = c2_0;
    t8_1 = c2_1;
    build_pre();
  }

  // W*: slot to overwrite with row m+4; R*: slot holding row m+1.
  auto row_body = [&](auto MODEC, int m, float2& WX, float2& WM,
                      const float2& RX, const float2& RM) {
    constexpr int MODE = decltype(MODEC)::value;
    constexpr bool FAST = (MODE < 2);
    const size_t nro = (size_t)((m + 4) & (NDIM - 1)) * NDIM;
    WX = *(const float2*)(xb + nro);
    WM = *(const float2*)(mb + nro);

    // ---- local wave scans (chain head) ----
    float PS = 0.0f;
    if constexpr (!FAST) PS = prefix_inc(S);
    float PA = prefix_inc(sa);

    if (lane == 63) {
      ex_sa[w] = PA;  // wave-inclusive total
      if constexpr (!FAST) ex_S[w] = PS;
    }
    wg_barrier();  // bar1: publish scan totals

    float4 sav = *(const float4*)ex_sa;
    float off_sa = 0.0f;
    if (w > 0) off_sa += sav.x;
    if (w > 1) off_sa += sav.y;
    if (w > 2) off_sa += sav.z;
    // linear entry guess: 1 - (global exclusive t8-prefix before this lane)
    float uin = fmaxf(1.0f - (off_sa + (PA - sa)), 0.0f);

    float R_ = 0.0f, mfm0 = 0.0f, mfm1 = 0.0f, nc1m0 = 0.0f, nc1m1 = 0.0f;
    if constexpr (!FAST) {
      float4 Sv = *(const float4*)ex_S;
      float Tg = (Sv.x + Sv.y) + (Sv.z + Sv.w);
      float off_S = 0.0f;
      if (w > 0) off_S += Sv.x;
      if (w > 1) off_S += Sv.y;
      if (w > 2) off_S += Sv.z;
      R_ = (Tg - off_S) - PS;  // future mass strictly after this lane
      mfm0 = R_ + suf0;
      mfm1 = R_;  // suf[1] = 0
      nc1m0 = -c1_0 * mfm0;
      nc1m1 = -c1_1 * mfm1;
    }

    // ---- parallel branch prediction (2 cells) ----
    bool pW0 = wp0 < uin;
    bool pW1 = wp1 < uin;
    float aP0 = pW0 ? 1.0f : oc2_0;
    float aP1 = pW1 ? 1.0f : oc2_1;
    float bP0 = pW0 ? (-t8_0) : 0.0f;
    float bP1 = pW1 ? (-t8_1) : 0.0f;
    if constexpr (!FAST) {
      float d = uin - R_;
      bool pL0 = d > sp0;
      bool pL1 = d > sp1;
      if (pL0) {
        aP0 -= c1_0;
        bP0 -= nc1m0;
      }
      if (pL1) {
        aP1 -= c1_1;
        bP1 -= nc1m1;
      }
    }

    // ---- pair compose + wave affine scan ----
    float A = aP1 * aP0;
    float Bv = fmaf(aP1, bP0, bP1);
    aff_step<0x111, 0xf>(A, Bv);
    aff_step<0x112, 0xf>(A, Bv);
    aff_step<0x114, 0xf>(A, Bv);
    aff_step<0x118, 0xf>(A, Bv);
    aff_step<0x142, 0xa>(A, Bv);
    aff_step<0x143, 0xc>(A, Bv);
    float Aex = wave_shr1(A, 1.0f);
    float Bex = wave_shr1(Bv, 0.0f);

    if (lane == 63) {
      ex_A[w] = A;  // wave-inclusive composition
      ex_B[w] = Bv;
    }
    wg_barrier();  // bar2: publish affine totals

    float4 eAv = *(const float4*)ex_A;
    float4 eBv = *(const float4*)ex_B;
    float E = 1.0f;  // row entry into this wave (unclamped, matches R13 math)
    if (w > 0) E = fmaf(eAv.x, E, eBv.x);
    if (w > 1) E = fmaf(eAv.y, E, eBv.y);
    if (w > 2) E = fmaf(eAv.z, E, eBv.z);
    float e = fminf(fmaxf(fmaf(Aex, E, Bex), 0.0f), 1.0f);  // lane entry

    // ---- row m+1 x-only prep (data loaded 3+ rows ago; off-chain) ----
    float c1n0 = 0.0f, c1n1 = 0.0f, c2n0, c2n1, oc2n0, oc2n1;
    float omn0 = 0.0f, omn1 = 0.0f;
    {
      float s0 = __builtin_amdgcn_rcpf(1.0f + __expf(-RX.x));
      float s1 = __builtin_amdgcn_rcpf(1.0f + __expf(-RX.y));
      c2n0 = RM.x * s0;
      c2n1 = RM.y * s1;
      oc2n0 = 1.0f - c2n0;
      oc2n1 = 1.0f - c2n1;
      if constexpr (MODE >= 1) {
        c1n0 = RM.x - c2n0;
        c1n1 = RM.y - c2n1;
      }
      if constexpr (MODE == 2) {
        omn0 = 1.0f - RM.x;
        omn1 = 1.0f - RM.y;
      }
    }

    // ---- within-lane entries + TRUE-branch outputs ----
    float uu0 = e;
    float uu1 = fmaxf(fmaf(aP0, e, bP0), 0.0f);
    float U0 = fminf(uu0, w8_0);
    float U1 = fminf(uu1, w8_1);
    float p0, p1;
    if constexpr (FAST) {
      p0 = c2_0 * U0;  // g == 0 provably on fast rows
      p1 = c2_1 * U1;
    } else {
      float g0 = fmaxf(fmaf(c1_0, uu0, nc1m0), 0.0f);
      float g1 = fmaxf(fmaf(c1_1, uu1, nc1m1), 0.0f);
      p0 = fmaf(c2_0, U0, g0);
      p1 = fmaf(c2_1, U1, g1);
    }
    w8_0 -= p0;
    w8_1 -= p1;
    *(float2*)(ob + (size_t)m * NDIM) = make_float2(p0, p1);

    // ---- next row's scan inputs (the real cross-row chain) ----
    t8_0 = c2n0 * w8_0;
    t8_1 = c2n1 * w8_1;
    build_pre();
    if constexpr (MODE == 2) {
      fu0 = fmaxf(w8_0 - omn0, 0.0f);
      fu1 = fmaxf(w8_1 - omn1, 0.0f);
      build_suf();
    }
    c2_0 = c2n0;
    c2_1 = c2n1;
    oc2_0 = oc2n0;
    oc2_1 = oc2n1;
    if constexpr (MODE >= 1) {
      c1_0 = c1n0;
      c1_1 = c1n1;
    }
  };

  using Fast0 = std::integral_constant<int, 0>;
  using Fast1 = std::integral_constant<int, 1>;
  using Full2 = std::integral_constant<int, 2>;

#pragma unroll 1
  for (int m = 0; m < 444; m += 4) {
    row_body(Fast0{}, m + 0, x0, m0, x1, m1);
    row_body(Fast0{}, m + 1, x1, m1, x2, m2);
    row_body(Fast0{}, m + 2, x2, m2, x3, m3);
    row_body(Fast0{}, m + 3, x3, m3, x0, m0);
  }
  // last fast group: also carries c1 forward for the bridge
  row_body(Fast1{}, 444, x0, m0, x1, m1);
  row_body(Fast1{}, 445, x1, m1, x2, m2);
  row_body(Fast1{}, 446, x2, m2, x3, m3);
  row_body(Fast1{}, 447, x3, m3, x0, m0);

  // bridge: rebuild fu/S/suf/sp for row 448 (om = 1 - mask = 1 - (c1+c2))
  {
    float om0 = 1.0f - c1_0 - c2_0;
    float om1 = 1.0f - c1_1 - c2_1;
    fu0 = fmaxf(w8_0 - om0, 0.0f);
    fu1 = fmaxf(w8_1 - om1, 0.0f);
    build_suf();
  }

#pragma unroll 1
  for (int m = 448; m < NDIM; m += 4) {
    row_body(Full2{}, m + 0, x0, m0, x1, m1);
    row_body(Full2{}, m + 1, x1, m1, x2, m2);
    row_body(Full2{}, m + 2, x2, m2, x3, m3);
    row_body(Full2{}, m + 3, x3, m3, x0, m0);
  }
}

extern "C" void kernel_launch(void* const* d_in, const int* in_sizes, int n_in,
                              void* d_out, int out_size, void* d_ws,
                              size_t ws_size, hipStream_t stream) {
  const float* x = (const float*)d_in[0];
  const float* xmask = (const float*)d_in[1];
  float* out = (float*)d_out;
  (void)in_sizes;
  (void)n_in;
  (void)out_size;
  (void)d_ws;
  (void)ws_size;
  hipLaunchKernelGGL(sb_kernel, dim3(NBATCH), dim3(256), 0, stream, x, xmask,
                     out);
}